// Round 15
// baseline (154.060 us; speedup 1.0000x reference)
//
#include <hip/hip_runtime.h>
#include <hip/hip_bf16.h>

#define HID 1024
#define NHEADS 16
#define DH 64
#define BB 2
#define LL 2048
#define MM (BB*LL)   // 4096 rows
#define EPSF 1e-5f

typedef __attribute__((ext_vector_type(8))) short bf16x8;
typedef __attribute__((ext_vector_type(4))) float f32x4;

#define MFMA16(A,Bf,C) __builtin_amdgcn_mfma_f32_16x16x32_bf16(A,Bf,C,0,0,0)
#define GLOAD_LDS16(G, Ld) \
  __builtin_amdgcn_global_load_lds((__attribute__((address_space(1))) const void*)(G), \
                                   (__attribute__((address_space(3))) void*)(Ld), 16, 0, 0)
#define PIN(v) asm("" : "+v"(v))   // pin loop-invariant addr in a VGPR (no remat)
// raw v_exp_f32: args here are in [-30,-13] (normal results) — OCML's
// range/denorm guard code (~12 VALU ops per call) is pure overhead.
#define EXP2R(x) ({ float _y; asm("v_exp_f32 %0, %1" : "=v"(_y) : "v"(x)); _y; })
// Publish/consume barrier for the 2-phase LDS double-buffer.
// MUST drain BOTH counters: vmcnt(0) completes our global_load_lds DMA
// (publish side); lgkmcnt(0) completes our ds_reads of the buffer that the
// next phase will overwrite (consume side). s_barrier alone does NOT wait
// on other waves' outstanding LDS ops — omitting lgkmcnt(0) is a cross-wave
// race (R14 post-timing divergence: DMA landed in a buffer still being read).
#define WAIT_VM0_BAR() do { \
    asm volatile("s_waitcnt vmcnt(0) lgkmcnt(0)" ::: "memory"); \
    __builtin_amdgcn_s_barrier(); \
    __builtin_amdgcn_sched_barrier(0); \
  } while (0)

__device__ __forceinline__ unsigned short f2bf(float f) {
  union { float f; unsigned int u; } x; x.f = f;
  unsigned int r = x.u + 0x7fffu + ((x.u >> 16) & 1u);
  return (unsigned short)(r >> 16);
}

// ---------------- uncertainty gate: u = relu(ue@Wu1+bu1); scale = sigmoid(u@Wu2+bu2)
__global__ __launch_bounds__(256) void u1_partial(const float* __restrict__ ue,
                                                  const float* __restrict__ Wu1,
                                                  float* __restrict__ upart) {
  int b = blockIdx.y, kb = blockIdx.x;           // kb: 0..7, 128 k each
  __shared__ float su[128];
  int tid = threadIdx.x;
  if (tid < 128) su[tid] = ue[b*HID + kb*128 + tid];
  __syncthreads();
  float s = 0.f;
  const float* w = Wu1 + (size_t)(kb*128)*256 + tid;  // column tid
  for (int k = 0; k < 128; ++k) s += su[k] * w[(size_t)k*256];
  upart[(b*8 + kb)*256 + tid] = s;
}

__global__ __launch_bounds__(256) void u2_scale(const float* __restrict__ upart,
                                                const float* __restrict__ bu1,
                                                const float* __restrict__ Wu2,
                                                const float* __restrict__ bu2,
                                                float* __restrict__ scale) {
  int b = blockIdx.x, tid = threadIdx.x;
  __shared__ float su[256];
  float s = 0.f;
  for (int kb = 0; kb < 8; ++kb) s += upart[(b*8 + kb)*256 + tid];
  su[tid] = fmaxf(s + bu1[tid], 0.f);
  __syncthreads();
  if (tid < 16) {
    float a = bu2[tid];
    for (int k = 0; k < 256; ++k) a += su[k] * Wu2[k*16 + tid];
    scale[b*NHEADS + tid] = 1.f / (1.f + __expf(-a));
  }
}

// ---------------- maskf[bh][k] = (amask==0 ? -1e9 : 0)*scale[bh]*log2e - CFIX
// CFIX=16: fixed softmax shift (shift-invariant; scores are O(1) in log2
// units, exp2(s-16) in [2^-20,2^-13] — no overflow/all-underflow here).
__global__ __launch_bounds__(256) void maskprep_kernel(const int* __restrict__ amask,
                                                       const float* __restrict__ scale,
                                                       float* __restrict__ maskf) {
  int i = blockIdx.x*256 + threadIdx.x;   // 8 elems each; total 32*2048
  int base = i*8;
  int bh = base >> 11;
  int b  = bh >> 4;
  float cm = scale[bh] * 1.44269504f;
  int k = base & (LL-1);
  #pragma unroll
  for (int j = 0; j < 8; ++j)
    maskf[base + j] = (amask[b*LL + k + j] == 0 ? -1e9f : 0.f) * cm - 16.f;
}

// ---------------- fp32 -> bf16 convert (hidden_state)
__global__ __launch_bounds__(256) void convert_x_kernel(const float* __restrict__ X,
                                                        unsigned short* __restrict__ Xb) {
  int i = blockIdx.x*256 + threadIdx.x;   // 4 elems each; grid sized exactly
  float4 v = ((const float4*)X)[i];
  ushort4 o; o.x = f2bf(v.x); o.y = f2bf(v.y); o.z = f2bf(v.z); o.w = f2bf(v.w);
  ((ushort4*)Xb)[i] = o;
}

// ---------------- W (K x N fp32) -> Wt (N x K bf16), z selects Wq/Wk/Wv/Wo
__global__ void transw_kernel(const float* __restrict__ Wq, const float* __restrict__ Wk,
                              const float* __restrict__ Wv, const float* __restrict__ Wo,
                              unsigned short* __restrict__ Wqkvt, unsigned short* __restrict__ Wot) {
  __shared__ float tile[32][33];
  int z = blockIdx.z;
  const float* W = (z==0) ? Wq : (z==1) ? Wk : (z==2) ? Wv : Wo;
  unsigned short* dst = (z < 3) ? (Wqkvt + (size_t)z*HID*HID) : Wot;
  int n0 = blockIdx.x*32, k0 = blockIdx.y*32;
  int tx = threadIdx.x, ty = threadIdx.y;      // 32 x 8
  #pragma unroll
  for (int i = 0; i < 4; ++i) tile[ty+8*i][tx] = W[(size_t)(k0+ty+8*i)*HID + n0+tx];
  __syncthreads();
  #pragma unroll
  for (int i = 0; i < 4; ++i) dst[(size_t)(n0+ty+8*i)*HID + k0+tx] = f2bf(tile[tx][ty+8*i]);
}

// ---------------- MFMA GEMM, 64x128 tile, BK=32, K=HID: C = A @ Bt^T
// 2-phase dbuf, one vmcnt(0)+lgkmcnt(0)+s_barrier per 32-K-step. LDS 24KB.
// 64B LDS rows, XOR-swizzle physical = row*64 + (colByte ^ (((row>>1)&3)<<4))
// MODE 0: grid 1536 (64m x 24n, 3 n-tiles/XCD); QKV -> bf16, V transposed.
// MODE 1: grid 512  (64m x 8n, 1 n-tile/XCD);  out-proj -> fp32 + residual.
template<int MODE>
__global__ __launch_bounds__(256) void gemm_kernel(
    const unsigned short* __restrict__ A,
    const unsigned short* __restrict__ Bt,
    const float* __restrict__ bias0, const float* __restrict__ bias1, const float* __restrict__ bias2,
    const float* __restrict__ resid,
    unsigned short* __restrict__ outQKV,
    float* __restrict__ outY) {
  constexpr int BM = 64;
  constexpr int MI = 2;                       // acc rows per wave
  constexpr int ASZ = BM*32*2;                // 4KB per A buffer
  constexpr int BSZ = 128*32*2;               // 8KB per B buffer
  __shared__ alignas(16) unsigned short sA[2*BM*32];
  __shared__ alignas(16) unsigned short sB[2*128*32];
  const int tid = threadIdx.x, lane = tid & 63, wv = tid >> 6;
  const int wr = wv >> 1, wc = wv & 1;
  const int bid = blockIdx.x, xcd = bid & 7, loc = bid >> 3;
  const int nIdx = (MODE == 0) ? (xcd*3 + loc % 3) : xcd;
  const int mIdx = (MODE == 0) ? (loc / 3) : loc;
  const int m0 = mIdx*BM, n0 = nIdx*128;
  const int r = lane & 15, g = lane >> 4;

  // staging pointers (advance += 32 per K-step); source pre-unswizzled
  const unsigned short* pA0;
  const unsigned short* pB[2];
  int ldsA0, ldsB[2];
  {
    const int base = wv*1024;                 // A: single 4KB chunk
    const int po = base + lane*16;
    const int uo = po ^ (((po>>7)&3)<<4);     // row = po>>6; swizzle on row>>1
    const int e  = uo >> 1;                   // row=e>>5, col=e&31
    pA0 = A + (size_t)(m0 + (e>>5))*HID + (e&31);
    ldsA0 = base;
  }
  #pragma unroll
  for (int c = 0; c < 2; ++c) {
    const int base = c*4096 + wv*1024;
    const int po = base + lane*16;
    const int uo = po ^ (((po>>7)&3)<<4);
    const int e  = uo >> 1;
    pB[c] = Bt + (size_t)(n0 + (e>>5))*HID + (e&31);
    ldsB[c] = base;
  }
  const int swz = ((r >> 1) & 3) << 4;        // row>>1 dep only (i/j*16 rows -> +8 ≡ 0 mod 4)
  int oA = (wr*(MI*16) + r)*64 + ((g*16) ^ swz);   // + i*1024 immediate
  int oB = (wc*64 + r)*64 + ((g*16) ^ swz);        // + j*1024 immediate
  PIN(oA); PIN(oB);

#define GSTAGE(BUF) do {                                                      \
    GLOAD_LDS16(pA0, (char*)sA + (BUF)*ASZ + ldsA0); pA0 += 32;               \
    _Pragma("unroll")                                                         \
    for (int c = 0; c < 2; ++c) {                                             \
      GLOAD_LDS16(pB[c], (char*)sB + (BUF)*BSZ + ldsB[c]); pB[c] += 32;       \
    }                                                                         \
  } while (0)

#define GCOMPUTE(BUF) do {                                                    \
    bf16x8 af[MI], bfv[4];                                                    \
    _Pragma("unroll")                                                         \
    for (int i = 0; i < MI; ++i)                                              \
      af[i]  = *(const bf16x8*)((const char*)sA + (BUF)*ASZ + oA + i*1024);   \
    _Pragma("unroll")                                                         \
    for (int j = 0; j < 4; ++j)                                               \
      bfv[j] = *(const bf16x8*)((const char*)sB + (BUF)*BSZ + oB + j*1024);   \
    __builtin_amdgcn_s_setprio(1);                                            \
    _Pragma("unroll")                                                         \
    for (int i = 0; i < MI; ++i)                                              \
      _Pragma("unroll")                                                       \
      for (int j = 0; j < 4; ++j)                                             \
        acc[i][j] = MFMA16(af[i], bfv[j], acc[i][j]);                         \
    __builtin_amdgcn_s_setprio(0);                                            \
  } while (0)

  f32x4 acc[MI][4];
  #pragma unroll
  for (int i = 0; i < MI; ++i)
    #pragma unroll
    for (int j = 0; j < 4; ++j) acc[i][j] = (f32x4){0.f,0.f,0.f,0.f};

  GSTAGE(0);                                  // prologue: K-step 0 -> buf0
  for (int k0 = 0; k0 < HID; k0 += 64) {      // 16 double-steps of 2x32
    WAIT_VM0_BAR();                           // buf0 ready (staged 1 phase ago)
    GSTAGE(1);
    GCOMPUTE(0);
    WAIT_VM0_BAR();                           // buf1 ready
    if (k0 + 64 < HID) GSTAGE(0);
    GCOMPUTE(1);
  }
#undef GSTAGE
#undef GCOMPUTE

  if (MODE == 0) {
    const int which = n0 >> 10;
    const float* bias = (which==0) ? bias0 : (which==1) ? bias1 : bias2;
    if (which < 2) {
      unsigned short* dst = outQKV + (size_t)which * ((size_t)MM*HID);
      #pragma unroll
      for (int i = 0; i < MI; ++i)
        #pragma unroll
        for (int j = 0; j < 4; ++j)
          #pragma unroll
          for (int rr = 0; rr < 4; ++rr) {
            int row = m0 + wr*(MI*16) + i*16 + g*4 + rr;
            int col = n0 + wc*64 + j*16 + r;
            int nn = col & (HID-1);
            int hh = nn >> 6, d = nn & 63;
            int bI = row >> 11, l = row & (LL-1);
            float v = acc[i][j][rr] + bias[nn];
            dst[(((size_t)(bI*NHEADS + hh)*LL + l) << 6) + d] = f2bf(v);
          }
    } else {
      unsigned short* dst = outQKV + 2*((size_t)MM*HID);
      #pragma unroll
      for (int i = 0; i < MI; ++i)
        #pragma unroll
        for (int j = 0; j < 4; ++j) {
          int col = n0 + wc*64 + j*16 + r;
          int nn = col & (HID-1);
          int hh = nn >> 6, d = nn & 63;
          int row0 = m0 + wr*(MI*16) + i*16 + g*4;
          int bI = row0 >> 11, l0 = row0 & (LL-1);
          ushort4 o4;
          o4.x = f2bf(acc[i][j][0] + bias[nn]);
          o4.y = f2bf(acc[i][j][1] + bias[nn]);
          o4.z = f2bf(acc[i][j][2] + bias[nn]);
          o4.w = f2bf(acc[i][j][3] + bias[nn]);
          *(ushort4*)(dst + ((size_t)((bI*NHEADS + hh)*DH + d))*LL + l0) = o4;
        }
    }
  } else {
    #pragma unroll
    for (int i = 0; i < MI; ++i)
      #pragma unroll
      for (int j = 0; j < 4; ++j)
        #pragma unroll
        for (int rr = 0; rr < 4; ++rr) {
          int row = m0 + wr*(MI*16) + i*16 + g*4 + rr;
          int col = n0 + wc*64 + j*16 + r;
          size_t idx = (size_t)row*HID + col;
          outY[idx] = acc[i][j][rr] + bias0[col] + resid[idx];
        }
  }
}

// ---------------- flash attention (R9 structure): block = (b,h, 64 q);
// 4 waves x 16 q. 2-phase gload_lds dbuf K+V (pre-swizzled source, linear
// dest), ONE vmcnt(0)+lgkmcnt(0)+s_barrier per tile; fixed-exponent softmax;
// l via persistent ones-MFMA; raw v_exp_f32. LDS 40KB = 4 blocks/CU.
__global__ __launch_bounds__(256, 4) void attn_kernel(
    const unsigned short* __restrict__ Qb,
    const unsigned short* __restrict__ Kb,
    const unsigned short* __restrict__ Vt,
    const float* __restrict__ maskf,
    const float* __restrict__ scale_ws,
    unsigned short* __restrict__ attnout) {
  __shared__ alignas(16) unsigned short sK[2*64*64];  // [buf][key][d] (swizzled)
  __shared__ alignas(16) unsigned short sV[2*64*64];  // [buf][d][key] (swizzled)
  __shared__ alignas(16) unsigned short sP[4][16*64]; // per-wave [q][key] (swizzled)
  const int p = blockIdx.x;
  const int bh = (p & 7)*4 + ((p >> 3) >> 5);
  const int q0 = ((p >> 3) & 31) * 64;
  const int b  = bh >> 4;
  const int tid = threadIdx.x, lane = tid & 63, wv = tid >> 6;
  const int r = lane & 15, g = lane >> 4;
  const size_t hoff = (size_t)bh * (LL*DH);
  const float c2 = 0.125f * scale_ws[bh] * 1.44269504f;
  const unsigned short* Kg = Kb + hoff;
  const unsigned short* Vg = Vt + hoff;
  const float* pm = maskf + (size_t)bh*LL + g*4;

  // staging: 2 gload_lds each for K and V; source pre-swizzled, dest linear
  const unsigned short* pKs[2];
  const unsigned short* pVs[2];
  int lbase[2];
  #pragma unroll
  for (int c = 0; c < 2; ++c) {
    const int base_ = c*4096 + wv*1024;
    const int po_ = base_ + lane*16;
    const int uo_ = po_ ^ (((po_>>7)&7)<<4);
    const int e_  = uo_ >> 1;                 // row=e>>6, col=e&63
    pKs[c] = Kg + (size_t)(e_>>6)*DH + (e_&63);
    pVs[c] = Vg + (size_t)(e_>>6)*LL + (e_&63);
    lbase[c] = base_;
  }

  // pinned LDS read bases (shared by sK, sV, sP via array base + offset)
  const int sw = (r & 7) << 4;
  int oLo = r*128 + ((g*16) ^ sw);
  int oHi = r*128 + ((64 + g*16) ^ sw);
  PIN(oLo); PIN(oHi);
  int wP[4];
  #pragma unroll
  for (int kt = 0; kt < 4; ++kt) {
    wP[kt] = r*128 + ((kt*32 + g*8) ^ sw);
    PIN(wP[kt]);
  }

  bf16x8 aQ[2];                // Q B-frags: col=q=lane&15, k contiguous
  {
    const int qrow = q0 + wv*16 + r;
    #pragma unroll
    for (int kc = 0; kc < 2; ++kc)
      aQ[kc] = *(const bf16x8*)(Qb + hoff + (size_t)qrow*DH + kc*32 + g*8);
  }
  const short ONE_BF = (short)0x3F80;
  const bf16x8 vone = {ONE_BF,ONE_BF,ONE_BF,ONE_BF,ONE_BF,ONE_BF,ONE_BF,ONE_BF};

  f32x4 accO[4];               // accO[j][rr]: q=r, d=j*16+g*4+rr
  #pragma unroll
  for (int j = 0; j < 4; ++j) accO[j] = (f32x4){0.f,0.f,0.f,0.f};
  f32x4 lsum = (f32x4){0.f,0.f,0.f,0.f};   // persistent denominator accumulator

  // prologue: stage tile 0 -> buf0; mask(0) -> regs
  #pragma unroll
  for (int c = 0; c < 2; ++c) {
    GLOAD_LDS16(pKs[c], (char*)sK + lbase[c]);
    GLOAD_LDS16(pVs[c], (char*)sV + lbase[c]);
    pKs[c] += 64*DH;  pVs[c] += 64;
  }
  float4 mreg[4];
  #pragma unroll
  for (int kt = 0; kt < 4; ++kt) mreg[kt] = *(const float4*)(pm + kt*16);
  pm += 64;

#define ATILE(CUROFF, NBOFF, T) do {                                          \
    WAIT_VM0_BAR();                       /* tile T staged & published */     \
    if ((T) + 1 < LL/64) {                /* stage T+1 -> other buffer */     \
      _Pragma("unroll")                                                       \
      for (int c = 0; c < 2; ++c) {                                           \
        GLOAD_LDS16(pKs[c], (char*)sK + (NBOFF) + lbase[c]);                  \
        GLOAD_LDS16(pVs[c], (char*)sV + (NBOFF) + lbase[c]);                  \
        pKs[c] += 64*DH;  pVs[c] += 64;                                       \
      }                                                                       \
    }                                                                         \
    f32x4 sc[4];                                                              \
    __builtin_amdgcn_s_setprio(1);                                            \
    _Pragma("unroll")                                                         \
    for (int kt = 0; kt < 4; ++kt) {                                          \
      bf16x8 bk0 = *(const bf16x8*)((const char*)sK + (CUROFF) + oLo + kt*2048); \
      bf16x8 bk1 = *(const bf16x8*)((const char*)sK + (CUROFF) + oHi + kt*2048); \
      f32x4 a = (f32x4){0.f,0.f,0.f,0.f};                                     \
      a = MFMA16(bk0, aQ[0], a);                                              \
      a = MFMA16(bk1, aQ[1], a);                                              \
      sc[kt] = a;                                                             \
    }                                                                         \
    __builtin_amdgcn_s_setprio(0);                                            \
    _Pragma("unroll")                                                         \
    for (int kt = 0; kt < 4; ++kt) {                                          \
      sc[kt][0] = EXP2R(sc[kt][0]*c2 + mreg[kt].x);                           \
      sc[kt][1] = EXP2R(sc[kt][1]*c2 + mreg[kt].y);                           \
      sc[kt][2] = EXP2R(sc[kt][2]*c2 + mreg[kt].z);                           \
      sc[kt][3] = EXP2R(sc[kt][3]*c2 + mreg[kt].w);                           \
    }                                                                         \
    if ((T) + 1 < LL/64) {                                                    \
      _Pragma("unroll")                                                       \
      for (int kt = 0; kt < 4; ++kt) mreg[kt] = *(const float4*)(pm + kt*16); \
      pm += 64;                                                               \
    }                                                                         \
    char* sPw = (char*)sP[wv];                                                \
    _Pragma("unroll")                                                         \
    for (int kt = 0; kt < 4; ++kt) {                                          \
      unsigned int lo, hi;                                                    \
      asm("v_cvt_pk_bf16_f32 %0, %1, %2" : "=v"(lo) : "v"(sc[kt][0]), "v"(sc[kt][1])); \
      asm("v_cvt_pk_bf16_f32 %0, %1, %2" : "=v"(hi) : "v"(sc[kt][2]), "v"(sc[kt][3])); \
      uint2 w; w.x = lo; w.y = hi;                                            \
      *(uint2*)(sPw + wP[kt]) = w;                                            \
    }                                                                         \
    bf16x8 aP0 = *(const bf16x8*)(sPw + oLo);                                 \
    bf16x8 aP1 = *(const bf16x8*)(sPw + oHi);                                 \
    lsum = MFMA16(vone, aP0, lsum);                                           \
    lsum = MFMA16(vone, aP1, lsum);                                           \
    __builtin_amdgcn_s_setprio(1);                                            \
    _Pragma("unroll")                                                         \
    for (int j = 0; j < 4; ++j) {                                             \
      bf16x8 v0 = *(const bf16x8*)((const char*)sV + (CUROFF) + oLo + j*2048); \
      bf16x8 v1 = *(const bf16x8*)((const char*)sV + (CUROFF) + oHi + j*2048); \
      accO[j] = MFMA16(v0, aP0, accO[j]);                                     \
      accO[j] = MFMA16(v1, aP1, accO[j]);                                     \
    }                                                                         \
    __builtin_amdgcn_s_setprio(0);                                            \
  } while (0)

  for (int t = 0; t < LL/64; t += 2) {
    ATILE(0,    8192, t);
    ATILE(8192, 0,    t+1);
  }
#undef ATILE

  // write (b, l, h*64+d) bf16; lane-local l, vectorized ushort4 stores
  const float invl = 1.f / lsum[0];
  const int qq = q0 + wv*16 + r;
  #pragma unroll
  for (int j = 0; j < 4; ++j) {
    ushort4 o4;
    o4.x = f2bf(accO[j][0] * invl);
    o4.y = f2bf(accO[j][1] * invl);
    o4.z = f2bf(accO[j][2] * invl);
    o4.w = f2bf(accO[j][3] * invl);
    const int col = (bh & 15)*DH + j*16 + g*4;
    *(ushort4*)(attnout + (size_t)(b*LL + qq)*HID + col) = o4;
  }
}

// ---------------- LayerNorm over last dim (1024), fp32 in/out (float4 loads)
__global__ __launch_bounds__(256) void ln_kernel(const float* __restrict__ Y,
                                                 const float* __restrict__ gamma,
                                                 const float* __restrict__ beta,
                                                 float* __restrict__ out) {
  int row = blockIdx.x, tid = threadIdx.x;
  const float4 v = ((const float4*)(Y + (size_t)row*HID))[tid];
  float s  = (v.x + v.y) + (v.z + v.w);
  float s2 = (v.x*v.x + v.y*v.y) + (v.z*v.z + v.w*v.w);
  #pragma unroll
  for (int o = 1; o < 64; o <<= 1) { s += __shfl_xor(s, o, 64); s2 += __shfl_xor(s2, o, 64); }
  __shared__ float ws1[4], ws2[4];
  if ((tid & 63) == 0) { ws1[tid>>6] = s; ws2[tid>>6] = s2; }
  __syncthreads();
  s  = ws1[0] + ws1[1] + ws1[2] + ws1[3];
  s2 = ws2[0] + ws2[1] + ws2[2] + ws2[3];
  float mu  = s * (1.f/HID);
  float var = s2 * (1.f/HID) - mu*mu;
  float rs  = rsqrtf(var + EPSF);
  const float4 gm = ((const float4*)gamma)[tid];
  const float4 bt = ((const float4*)beta)[tid];
  float4 o4;
  o4.x = (v.x - mu)*rs*gm.x + bt.x;
  o4.y = (v.y - mu)*rs*gm.y + bt.y;
  o4.z = (v.z - mu)*rs*gm.z + bt.z;
  o4.w = (v.w - mu)*rs*gm.w + bt.w;
  ((float4*)(out + (size_t)row*HID))[tid] = o4;
}

extern "C" void kernel_launch(void* const* d_in, const int* in_sizes, int n_in,
                              void* d_out, int out_size, void* d_ws, size_t ws_size,
                              hipStream_t stream) {
  const float* hidden = (const float*)d_in[0];
  const float* ue     = (const float*)d_in[1];
  const int*   amask  = (const int*)d_in[2];
  const float* Wq = (const float*)d_in[3];  const float* bq = (const float*)d_in[4];
  const float* Wk = (const float*)d_in[5];  const float* bk = (const float*)d_in[6];
  const float* Wv = (const float*)d_in[7];  const float* bv = (const float*)d_in[8];
  const float* Wo = (const float*)d_in[9];  const float* bo = (const float*)d_in[10];
  const float* Wu1 = (const float*)d_in[11]; const float* bu1 = (const float*)d_in[12];
  const float* Wu2 = (const float*)d_in[13]; const float* bu2 = (const float*)d_in[14];
  const float* gamma = (const float*)d_in[15]; const float* beta = (const float*)d_in[16];
  float* out = (float*)d_out;

  // workspace layout (needs ~57 MB)
  char* ws = (char*)d_ws;
  if (ws_size < ((56u<<20) + 32768)) return;
  unsigned short* Xbf   = (unsigned short*)(ws + 0);            // 8 MB (dead after QKV gemm)
  float*          Y     = (float*)(ws + 0);                     // 16 MB (written by gemm1, after attn)
  float*          maskf = (float*)(ws + (8u<<20));              // 256 KB (dead once gemm1 writes Y)
  unsigned short* Wqkvt = (unsigned short*)(ws + (16u<<20));    // 6 MB
  unsigned short* Wot   = (unsigned short*)(ws + (22u<<20));    // 2 MB
  unsigned short* Qb    = (unsigned short*)(ws + (24u<<20));    // 8 MB each
  unsigned short* Kb    = Qb + (size_t)MM*HID;
  unsigned short* Vb    = Kb + (size_t)MM*HID;                  // V^T (b,h,d,l)
  unsigned short* AOut  = (unsigned short*)(ws + (48u<<20));    // 8 MB
  float* upart = (float*)(ws + (56u<<20));                      // 16 KB
  float* scale = upart + BB*8*256;                              // 32 floats

  u1_partial<<<dim3(8, BB), 256, 0, stream>>>(ue, Wu1, upart);
  u2_scale<<<BB, 256, 0, stream>>>(upart, bu1, Wu2, bu2, scale);
  maskprep_kernel<<<(BB*NHEADS*LL/8)/256, 256, 0, stream>>>(amask, scale, maskf);
  convert_x_kernel<<<(MM*HID/4)/256, 256, 0, stream>>>(hidden, Xbf);
  transw_kernel<<<dim3(32, 32, 4), dim3(32, 8), 0, stream>>>(Wq, Wk, Wv, Wo, Wqkvt, Wot);
  gemm_kernel<0><<<1536, 256, 0, stream>>>(Xbf, Wqkvt,
                                           bq, bk, bv, nullptr, Qb, nullptr);
  attn_kernel<<<BB*NHEADS*(LL/64), 256, 0, stream>>>(Qb, Kb, Vb, maskf, scale, AOut);
  gemm_kernel<1><<<512, 256, 0, stream>>>(AOut, Wot,
                                          bo, nullptr, nullptr, hidden, nullptr, Y);
  ln_kernel<<<MM, 256, 0, stream>>>(Y, gamma, beta, out);
}

// Round 16
// 153.032 us; speedup vs baseline: 1.0067x; 1.0067x over previous
//
#include <hip/hip_runtime.h>
#include <hip/hip_bf16.h>

#define HID 1024
#define NHEADS 16
#define DH 64
#define BB 2
#define LL 2048
#define MM (BB*LL)   // 4096 rows
#define EPSF 1e-5f

typedef __attribute__((ext_vector_type(8))) short bf16x8;
typedef __attribute__((ext_vector_type(4))) float f32x4;

#define MFMA16(A,Bf,C) __builtin_amdgcn_mfma_f32_16x16x32_bf16(A,Bf,C,0,0,0)
#define GLOAD_LDS16(G, Ld) \
  __builtin_amdgcn_global_load_lds((__attribute__((address_space(1))) const void*)(G), \
                                   (__attribute__((address_space(3))) void*)(Ld), 16, 0, 0)
#define PIN(v) asm("" : "+v"(v))   // pin loop-invariant addr in a VGPR (no remat)
// raw v_exp_f32: args here are in [-30,-13] (normal results) — OCML's
// range/denorm guard code (~12 VALU ops per call) is pure overhead.
#define EXP2R(x) ({ float _y; asm("v_exp_f32 %0, %1" : "=v"(_y) : "v"(x)); _y; })
// Publish/consume barrier, counted VMEM wait (T4): allow N loads to stay in
// flight, drain the rest; lgkmcnt(0) completes our ds_reads of the buffer the
// next stage will overwrite (cross-wave race otherwise — R14 lesson).
#define GWAIT_BAR(N) do { \
    asm volatile("s_waitcnt vmcnt(" #N ") lgkmcnt(0)" ::: "memory"); \
    __builtin_amdgcn_s_barrier(); \
    __builtin_amdgcn_sched_barrier(0); \
  } while (0)

__device__ __forceinline__ unsigned short f2bf(float f) {
  union { float f; unsigned int u; } x; x.f = f;
  unsigned int r = x.u + 0x7fffu + ((x.u >> 16) & 1u);
  return (unsigned short)(r >> 16);
}

// ---------------- uncertainty gate: u = relu(ue@Wu1+bu1); scale = sigmoid(u@Wu2+bu2)
__global__ __launch_bounds__(256) void u1_partial(const float* __restrict__ ue,
                                                  const float* __restrict__ Wu1,
                                                  float* __restrict__ upart) {
  int b = blockIdx.y, kb = blockIdx.x;           // kb: 0..7, 128 k each
  __shared__ float su[128];
  int tid = threadIdx.x;
  if (tid < 128) su[tid] = ue[b*HID + kb*128 + tid];
  __syncthreads();
  float s = 0.f;
  const float* w = Wu1 + (size_t)(kb*128)*256 + tid;  // column tid
  for (int k = 0; k < 128; ++k) s += su[k] * w[(size_t)k*256];
  upart[(b*8 + kb)*256 + tid] = s;
}

__global__ __launch_bounds__(256) void u2_scale(const float* __restrict__ upart,
                                                const float* __restrict__ bu1,
                                                const float* __restrict__ Wu2,
                                                const float* __restrict__ bu2,
                                                float* __restrict__ scale) {
  int b = blockIdx.x, tid = threadIdx.x;
  __shared__ float su[256];
  float s = 0.f;
  for (int kb = 0; kb < 8; ++kb) s += upart[(b*8 + kb)*256 + tid];
  su[tid] = fmaxf(s + bu1[tid], 0.f);
  __syncthreads();
  if (tid < 16) {
    float a = bu2[tid];
    for (int k = 0; k < 256; ++k) a += su[k] * Wu2[k*16 + tid];
    scale[b*NHEADS + tid] = 1.f / (1.f + __expf(-a));
  }
}

// ---------------- maskf[bh][k] = (amask==0 ? -1e9 : 0)*scale[bh]*log2e - CFIX
// CFIX=16: fixed softmax shift (shift-invariant; scores are O(1) in log2
// units, exp2(s-16) in [2^-20,2^-13] — no overflow/all-underflow here).
__global__ __launch_bounds__(256) void maskprep_kernel(const int* __restrict__ amask,
                                                       const float* __restrict__ scale,
                                                       float* __restrict__ maskf) {
  int i = blockIdx.x*256 + threadIdx.x;   // 8 elems each; total 32*2048
  int base = i*8;
  int bh = base >> 11;
  int b  = bh >> 4;
  float cm = scale[bh] * 1.44269504f;
  int k = base & (LL-1);
  #pragma unroll
  for (int j = 0; j < 8; ++j)
    maskf[base + j] = (amask[b*LL + k + j] == 0 ? -1e9f : 0.f) * cm - 16.f;
}

// ---------------- fp32 -> bf16 convert (hidden_state)
__global__ __launch_bounds__(256) void convert_x_kernel(const float* __restrict__ X,
                                                        unsigned short* __restrict__ Xb) {
  int i = blockIdx.x*256 + threadIdx.x;   // 4 elems each; grid sized exactly
  float4 v = ((const float4*)X)[i];
  ushort4 o; o.x = f2bf(v.x); o.y = f2bf(v.y); o.z = f2bf(v.z); o.w = f2bf(v.w);
  ((ushort4*)Xb)[i] = o;
}

// ---------------- W (K x N fp32) -> Wt (N x K bf16), z selects Wq/Wk/Wv/Wo
__global__ void transw_kernel(const float* __restrict__ Wq, const float* __restrict__ Wk,
                              const float* __restrict__ Wv, const float* __restrict__ Wo,
                              unsigned short* __restrict__ Wqkvt, unsigned short* __restrict__ Wot) {
  __shared__ float tile[32][33];
  int z = blockIdx.z;
  const float* W = (z==0) ? Wq : (z==1) ? Wk : (z==2) ? Wv : Wo;
  unsigned short* dst = (z < 3) ? (Wqkvt + (size_t)z*HID*HID) : Wot;
  int n0 = blockIdx.x*32, k0 = blockIdx.y*32;
  int tx = threadIdx.x, ty = threadIdx.y;      // 32 x 8
  #pragma unroll
  for (int i = 0; i < 4; ++i) tile[ty+8*i][tx] = W[(size_t)(k0+ty+8*i)*HID + n0+tx];
  __syncthreads();
  #pragma unroll
  for (int i = 0; i < 4; ++i) dst[(size_t)(n0+ty+8*i)*HID + k0+tx] = f2bf(tile[tx][ty+8*i]);
}

// ---------------- MFMA GEMM, 64x128 tile, BK=32, K=HID: C = A @ Bt^T
// T3+T4 proper: 4 LDS buffers, 3-deep prefetch, counted vmcnt(6) per step
// (never 0 in the main loop) — stage k's loads were issued 3 phases (~450cy)
// earlier, so the wait is ~free. Each stage = exactly 3 global_load_lds/wave.
// Epilogue drains 6 -> 6 -> 3 -> 0. LDS 48KB. 64B rows, XOR-swizzle
// physical = row*64 + (colByte ^ (((row>>1)&3)<<4)).
// MODE 0: grid 1536 (64m x 24n, 3 n-tiles/XCD); QKV -> bf16, V transposed.
// MODE 1: grid 512  (64m x 8n, 1 n-tile/XCD);  out-proj -> fp32 + residual.
template<int MODE>
__global__ __launch_bounds__(256) void gemm_kernel(
    const unsigned short* __restrict__ A,
    const unsigned short* __restrict__ Bt,
    const float* __restrict__ bias0, const float* __restrict__ bias1, const float* __restrict__ bias2,
    const float* __restrict__ resid,
    unsigned short* __restrict__ outQKV,
    float* __restrict__ outY) {
  constexpr int BM = 64;
  constexpr int MI = 2;                       // acc rows per wave
  constexpr int ASZ = BM*32*2;                // 4KB per A buffer
  constexpr int BSZ = 128*32*2;               // 8KB per B buffer
  __shared__ alignas(16) unsigned short sA[4*BM*32];
  __shared__ alignas(16) unsigned short sB[4*128*32];
  const int tid = threadIdx.x, lane = tid & 63, wv = tid >> 6;
  const int wr = wv >> 1, wc = wv & 1;
  const int bid = blockIdx.x, xcd = bid & 7, loc = bid >> 3;
  const int nIdx = (MODE == 0) ? (xcd*3 + loc % 3) : xcd;
  const int mIdx = (MODE == 0) ? (loc / 3) : loc;
  const int m0 = mIdx*BM, n0 = nIdx*128;
  const int r = lane & 15, g = lane >> 4;

  // staging pointers (advance += 32 per K-step); source pre-unswizzled
  const unsigned short* pA0;
  const unsigned short* pB[2];
  int ldsA0, ldsB[2];
  {
    const int base = wv*1024;                 // A: single 4KB chunk
    const int po = base + lane*16;
    const int uo = po ^ (((po>>7)&3)<<4);     // row = po>>6; swizzle on row>>1
    const int e  = uo >> 1;                   // row=e>>5, col=e&31
    pA0 = A + (size_t)(m0 + (e>>5))*HID + (e&31);
    ldsA0 = base;
  }
  #pragma unroll
  for (int c = 0; c < 2; ++c) {
    const int base = c*4096 + wv*1024;
    const int po = base + lane*16;
    const int uo = po ^ (((po>>7)&3)<<4);
    const int e  = uo >> 1;
    pB[c] = Bt + (size_t)(n0 + (e>>5))*HID + (e&31);
    ldsB[c] = base;
  }
  const int swz = ((r >> 1) & 3) << 4;        // row>>1 dep only (i/j*16 rows -> +8 ≡ 0 mod 4)
  int oA = (wr*(MI*16) + r)*64 + ((g*16) ^ swz);   // + i*1024 immediate
  int oB = (wc*64 + r)*64 + ((g*16) ^ swz);        // + j*1024 immediate
  PIN(oA); PIN(oB);

#define GSTAGE(BUF) do {                                                      \
    GLOAD_LDS16(pA0, (char*)sA + (BUF)*ASZ + ldsA0); pA0 += 32;               \
    _Pragma("unroll")                                                         \
    for (int c = 0; c < 2; ++c) {                                             \
      GLOAD_LDS16(pB[c], (char*)sB + (BUF)*BSZ + ldsB[c]); pB[c] += 32;       \
    }                                                                         \
  } while (0)

#define GCOMPUTE(BUF) do {                                                    \
    bf16x8 af[MI], bfv[4];                                                    \
    _Pragma("unroll")                                                         \
    for (int i = 0; i < MI; ++i)                                              \
      af[i]  = *(const bf16x8*)((const char*)sA + (BUF)*ASZ + oA + i*1024);   \
    _Pragma("unroll")                                                         \
    for (int j = 0; j < 4; ++j)                                               \
      bfv[j] = *(const bf16x8*)((const char*)sB + (BUF)*BSZ + oB + j*1024);   \
    __builtin_amdgcn_s_setprio(1);                                            \
    _Pragma("unroll")                                                         \
    for (int i = 0; i < MI; ++i)                                              \
      _Pragma("unroll")                                                       \
      for (int j = 0; j < 4; ++j)                                             \
        acc[i][j] = MFMA16(af[i], bfv[j], acc[i][j]);                         \
    __builtin_amdgcn_s_setprio(0);                                            \
  } while (0)

  f32x4 acc[MI][4];
  #pragma unroll
  for (int i = 0; i < MI; ++i)
    #pragma unroll
    for (int j = 0; j < 4; ++j) acc[i][j] = (f32x4){0.f,0.f,0.f,0.f};

  // 32 K-steps; step k computes buf k%4, stages step k+3 into buf (k+3)%4.
  GSTAGE(0); GSTAGE(1); GSTAGE(2);            // prologue: 9 loads in flight
  #pragma unroll 1
  for (int it = 0; it < 7; ++it) {            // k = 0..27
    GWAIT_BAR(6); GSTAGE(3); GCOMPUTE(0);
    GWAIT_BAR(6); GSTAGE(0); GCOMPUTE(1);
    GWAIT_BAR(6); GSTAGE(1); GCOMPUTE(2);
    GWAIT_BAR(6); GSTAGE(2); GCOMPUTE(3);
  }
  GWAIT_BAR(6); GSTAGE(3); GCOMPUTE(0);       // k=28 (stage 31)
  GWAIT_BAR(6); GCOMPUTE(1);                  // k=29
  GWAIT_BAR(3); GCOMPUTE(2);                  // k=30
  GWAIT_BAR(0); GCOMPUTE(3);                  // k=31
#undef GSTAGE
#undef GCOMPUTE

  if (MODE == 0) {
    const int which = n0 >> 10;
    const float* bias = (which==0) ? bias0 : (which==1) ? bias1 : bias2;
    if (which < 2) {
      unsigned short* dst = outQKV + (size_t)which * ((size_t)MM*HID);
      #pragma unroll
      for (int i = 0; i < MI; ++i)
        #pragma unroll
        for (int j = 0; j < 4; ++j)
          #pragma unroll
          for (int rr = 0; rr < 4; ++rr) {
            int row = m0 + wr*(MI*16) + i*16 + g*4 + rr;
            int col = n0 + wc*64 + j*16 + r;
            int nn = col & (HID-1);
            int hh = nn >> 6, d = nn & 63;
            int bI = row >> 11, l = row & (LL-1);
            float v = acc[i][j][rr] + bias[nn];
            dst[(((size_t)(bI*NHEADS + hh)*LL + l) << 6) + d] = f2bf(v);
          }
    } else {
      unsigned short* dst = outQKV + 2*((size_t)MM*HID);
      #pragma unroll
      for (int i = 0; i < MI; ++i)
        #pragma unroll
        for (int j = 0; j < 4; ++j) {
          int col = n0 + wc*64 + j*16 + r;
          int nn = col & (HID-1);
          int hh = nn >> 6, d = nn & 63;
          int row0 = m0 + wr*(MI*16) + i*16 + g*4;
          int bI = row0 >> 11, l0 = row0 & (LL-1);
          ushort4 o4;
          o4.x = f2bf(acc[i][j][0] + bias[nn]);
          o4.y = f2bf(acc[i][j][1] + bias[nn]);
          o4.z = f2bf(acc[i][j][2] + bias[nn]);
          o4.w = f2bf(acc[i][j][3] + bias[nn]);
          *(ushort4*)(dst + ((size_t)((bI*NHEADS + hh)*DH + d))*LL + l0) = o4;
        }
    }
  } else {
    #pragma unroll
    for (int i = 0; i < MI; ++i)
      #pragma unroll
      for (int j = 0; j < 4; ++j)
        #pragma unroll
        for (int rr = 0; rr < 4; ++rr) {
          int row = m0 + wr*(MI*16) + i*16 + g*4 + rr;
          int col = n0 + wc*64 + j*16 + r;
          size_t idx = (size_t)row*HID + col;
          outY[idx] = acc[i][j][rr] + bias0[col] + resid[idx];
        }
  }
}

// ---------------- flash attention (R9 structure): block = (b,h, 64 q);
// 4 waves x 16 q. 2-phase gload_lds dbuf K+V (pre-swizzled source, linear
// dest), ONE vmcnt(0)+lgkmcnt(0)+s_barrier per tile (compute phase ~1500cy
// covers load latency, so drain-0 is cheap here); fixed-exponent softmax;
// l via persistent ones-MFMA; raw v_exp_f32. LDS 40KB = 4 blocks/CU.
__global__ __launch_bounds__(256, 4) void attn_kernel(
    const unsigned short* __restrict__ Qb,
    const unsigned short* __restrict__ Kb,
    const unsigned short* __restrict__ Vt,
    const float* __restrict__ maskf,
    const float* __restrict__ scale_ws,
    unsigned short* __restrict__ attnout) {
  __shared__ alignas(16) unsigned short sK[2*64*64];  // [buf][key][d] (swizzled)
  __shared__ alignas(16) unsigned short sV[2*64*64];  // [buf][d][key] (swizzled)
  __shared__ alignas(16) unsigned short sP[4][16*64]; // per-wave [q][key] (swizzled)
  const int p = blockIdx.x;
  const int bh = (p & 7)*4 + ((p >> 3) >> 5);
  const int q0 = ((p >> 3) & 31) * 64;
  const int b  = bh >> 4;
  const int tid = threadIdx.x, lane = tid & 63, wv = tid >> 6;
  const int r = lane & 15, g = lane >> 4;
  const size_t hoff = (size_t)bh * (LL*DH);
  const float c2 = 0.125f * scale_ws[bh] * 1.44269504f;
  const unsigned short* Kg = Kb + hoff;
  const unsigned short* Vg = Vt + hoff;
  const float* pm = maskf + (size_t)bh*LL + g*4;

  // staging: 2 gload_lds each for K and V; source pre-swizzled, dest linear
  const unsigned short* pKs[2];
  const unsigned short* pVs[2];
  int lbase[2];
  #pragma unroll
  for (int c = 0; c < 2; ++c) {
    const int base_ = c*4096 + wv*1024;
    const int po_ = base_ + lane*16;
    const int uo_ = po_ ^ (((po_>>7)&7)<<4);
    const int e_  = uo_ >> 1;                 // row=e>>6, col=e&63
    pKs[c] = Kg + (size_t)(e_>>6)*DH + (e_&63);
    pVs[c] = Vg + (size_t)(e_>>6)*LL + (e_&63);
    lbase[c] = base_;
  }

  // pinned LDS read bases (shared by sK, sV, sP via array base + offset)
  const int sw = (r & 7) << 4;
  int oLo = r*128 + ((g*16) ^ sw);
  int oHi = r*128 + ((64 + g*16) ^ sw);
  PIN(oLo); PIN(oHi);
  int wP[4];
  #pragma unroll
  for (int kt = 0; kt < 4; ++kt) {
    wP[kt] = r*128 + ((kt*32 + g*8) ^ sw);
    PIN(wP[kt]);
  }

  bf16x8 aQ[2];                // Q B-frags: col=q=lane&15, k contiguous
  {
    const int qrow = q0 + wv*16 + r;
    #pragma unroll
    for (int kc = 0; kc < 2; ++kc)
      aQ[kc] = *(const bf16x8*)(Qb + hoff + (size_t)qrow*DH + kc*32 + g*8);
  }
  const short ONE_BF = (short)0x3F80;
  const bf16x8 vone = {ONE_BF,ONE_BF,ONE_BF,ONE_BF,ONE_BF,ONE_BF,ONE_BF,ONE_BF};

  f32x4 accO[4];               // accO[j][rr]: q=r, d=j*16+g*4+rr
  #pragma unroll
  for (int j = 0; j < 4; ++j) accO[j] = (f32x4){0.f,0.f,0.f,0.f};
  f32x4 lsum = (f32x4){0.f,0.f,0.f,0.f};   // persistent denominator accumulator

  // prologue: stage tile 0 -> buf0; mask(0) -> regs
  #pragma unroll
  for (int c = 0; c < 2; ++c) {
    GLOAD_LDS16(pKs[c], (char*)sK + lbase[c]);
    GLOAD_LDS16(pVs[c], (char*)sV + lbase[c]);
    pKs[c] += 64*DH;  pVs[c] += 64;
  }
  float4 mreg[4];
  #pragma unroll
  for (int kt = 0; kt < 4; ++kt) mreg[kt] = *(const float4*)(pm + kt*16);
  pm += 64;

#define ATILE(CUROFF, NBOFF, T) do {                                          \
    GWAIT_BAR(0);                       /* tile T staged & published */       \
    if ((T) + 1 < LL/64) {              /* stage T+1 -> other buffer */       \
      _Pragma("unroll")                                                       \
      for (int c = 0; c < 2; ++c) {                                           \
        GLOAD_LDS16(pKs[c], (char*)sK + (NBOFF) + lbase[c]);                  \
        GLOAD_LDS16(pVs[c], (char*)sV + (NBOFF) + lbase[c]);                  \
        pKs[c] += 64*DH;  pVs[c] += 64;                                       \
      }                                                                       \
    }                                                                         \
    f32x4 sc[4];                                                              \
    __builtin_amdgcn_s_setprio(1);                                            \
    _Pragma("unroll")                                                         \
    for (int kt = 0; kt < 4; ++kt) {                                          \
      bf16x8 bk0 = *(const bf16x8*)((const char*)sK + (CUROFF) + oLo + kt*2048); \
      bf16x8 bk1 = *(const bf16x8*)((const char*)sK + (CUROFF) + oHi + kt*2048); \
      f32x4 a = (f32x4){0.f,0.f,0.f,0.f};                                     \
      a = MFMA16(bk0, aQ[0], a);                                              \
      a = MFMA16(bk1, aQ[1], a);                                              \
      sc[kt] = a;                                                             \
    }                                                                         \
    __builtin_amdgcn_s_setprio(0);                                            \
    _Pragma("unroll")                                                         \
    for (int kt = 0; kt < 4; ++kt) {                                          \
      sc[kt][0] = EXP2R(sc[kt][0]*c2 + mreg[kt].x);                           \
      sc[kt][1] = EXP2R(sc[kt][1]*c2 + mreg[kt].y);                           \
      sc[kt][2] = EXP2R(sc[kt][2]*c2 + mreg[kt].z);                           \
      sc[kt][3] = EXP2R(sc[kt][3]*c2 + mreg[kt].w);                           \
    }                                                                         \
    if ((T) + 1 < LL/64) {                                                    \
      _Pragma("unroll")                                                       \
      for (int kt = 0; kt < 4; ++kt) mreg[kt] = *(const float4*)(pm + kt*16); \
      pm += 64;                                                               \
    }                                                                         \
    char* sPw = (char*)sP[wv];                                                \
    _Pragma("unroll")                                                         \
    for (int kt = 0; kt < 4; ++kt) {                                          \
      unsigned int lo, hi;                                                    \
      asm("v_cvt_pk_bf16_f32 %0, %1, %2" : "=v"(lo) : "v"(sc[kt][0]), "v"(sc[kt][1])); \
      asm("v_cvt_pk_bf16_f32 %0, %1, %2" : "=v"(hi) : "v"(sc[kt][2]), "v"(sc[kt][3])); \
      uint2 w; w.x = lo; w.y = hi;                                            \
      *(uint2*)(sPw + wP[kt]) = w;                                            \
    }                                                                         \
    bf16x8 aP0 = *(const bf16x8*)(sPw + oLo);                                 \
    bf16x8 aP1 = *(const bf16x8*)(sPw + oHi);                                 \
    lsum = MFMA16(vone, aP0, lsum);                                           \
    lsum = MFMA16(vone, aP1, lsum);                                           \
    __builtin_amdgcn_s_setprio(1);                                            \
    _Pragma("unroll")                                                         \
    for (int j = 0; j < 4; ++j) {                                             \
      bf16x8 v0 = *(const bf16x8*)((const char*)sV + (CUROFF) + oLo + j*2048); \
      bf16x8 v1 = *(const bf16x8*)((const char*)sV + (CUROFF) + oHi + j*2048); \
      accO[j] = MFMA16(v0, aP0, accO[j]);                                     \
      accO[j] = MFMA16(v1, aP1, accO[j]);                                     \
    }                                                                         \
    __builtin_amdgcn_s_setprio(0);                                            \
  } while (0)

  for (int t = 0; t < LL/64; t += 2) {
    ATILE(0,    8192, t);
    ATILE(8192, 0,    t+1);
  }
#undef ATILE

  // write (b, l, h*64+d) bf16; lane-local l, vectorized ushort4 stores
  const float invl = 1.f / lsum[0];
  const int qq = q0 + wv*16 + r;
  #pragma unroll
  for (int j = 0; j < 4; ++j) {
    ushort4 o4;
    o4.x = f2bf(accO[j][0] * invl);
    o4.y = f2bf(accO[j][1] * invl);
    o4.z = f2bf(accO[j][2] * invl);
    o4.w = f2bf(accO[j][3] * invl);
    const int col = (bh & 15)*DH + j*16 + g*4;
    *(ushort4*)(attnout + (size_t)(b*LL + qq)*HID + col) = o4;
  }
}

// ---------------- LayerNorm over last dim (1024), fp32 in/out (float4 loads)
__global__ __launch_bounds__(256) void ln_kernel(const float* __restrict__ Y,
                                                 const float* __restrict__ gamma,
                                                 const float* __restrict__ beta,
                                                 float* __restrict__ out) {
  int row = blockIdx.x, tid = threadIdx.x;
  const float4 v = ((const float4*)(Y + (size_t)row*HID))[tid];
  float s  = (v.x + v.y) + (v.z + v.w);
  float s2 = (v.x*v.x + v.y*v.y) + (v.z*v.z + v.w*v.w);
  #pragma unroll
  for (int o = 1; o < 64; o <<= 1) { s += __shfl_xor(s, o, 64); s2 += __shfl_xor(s2, o, 64); }
  __shared__ float ws1[4], ws2[4];
  if ((tid & 63) == 0) { ws1[tid>>6] = s; ws2[tid>>6] = s2; }
  __syncthreads();
  s  = ws1[0] + ws1[1] + ws1[2] + ws1[3];
  s2 = ws2[0] + ws2[1] + ws2[2] + ws2[3];
  float mu  = s * (1.f/HID);
  float var = s2 * (1.f/HID) - mu*mu;
  float rs  = rsqrtf(var + EPSF);
  const float4 gm = ((const float4*)gamma)[tid];
  const float4 bt = ((const float4*)beta)[tid];
  float4 o4;
  o4.x = (v.x - mu)*rs*gm.x + bt.x;
  o4.y = (v.y - mu)*rs*gm.y + bt.y;
  o4.z = (v.z - mu)*rs*gm.z + bt.z;
  o4.w = (v.w - mu)*rs*gm.w + bt.w;
  ((float4*)(out + (size_t)row*HID))[tid] = o4;
}

extern "C" void kernel_launch(void* const* d_in, const int* in_sizes, int n_in,
                              void* d_out, int out_size, void* d_ws, size_t ws_size,
                              hipStream_t stream) {
  const float* hidden = (const float*)d_in[0];
  const float* ue     = (const float*)d_in[1];
  const int*   amask  = (const int*)d_in[2];
  const float* Wq = (const float*)d_in[3];  const float* bq = (const float*)d_in[4];
  const float* Wk = (const float*)d_in[5];  const float* bk = (const float*)d_in[6];
  const float* Wv = (const float*)d_in[7];  const float* bv = (const float*)d_in[8];
  const float* Wo = (const float*)d_in[9];  const float* bo = (const float*)d_in[10];
  const float* Wu1 = (const float*)d_in[11]; const float* bu1 = (const float*)d_in[12];
  const float* Wu2 = (const float*)d_in[13]; const float* bu2 = (const float*)d_in[14];
  const float* gamma = (const float*)d_in[15]; const float* beta = (const float*)d_in[16];
  float* out = (float*)d_out;

  // workspace layout (needs ~57 MB)
  char* ws = (char*)d_ws;
  if (ws_size < ((56u<<20) + 32768)) return;
  unsigned short* Xbf   = (unsigned short*)(ws + 0);            // 8 MB (dead after QKV gemm)
  float*          Y     = (float*)(ws + 0);                     // 16 MB (written by gemm1, after attn)
  float*          maskf = (float*)(ws + (8u<<20));              // 256 KB (dead once gemm1 writes Y)
  unsigned short* Wqkvt = (unsigned short*)(ws + (16u<<20));    // 6 MB
  unsigned short* Wot   = (unsigned short*)(ws + (22u<<20));    // 2 MB
  unsigned short* Qb    = (unsigned short*)(ws + (24u<<20));    // 8 MB each
  unsigned short* Kb    = Qb + (size_t)MM*HID;
  unsigned short* Vb    = Kb + (size_t)MM*HID;                  // V^T (b,h,d,l)
  unsigned short* AOut  = (unsigned short*)(ws + (48u<<20));    // 8 MB
  float* upart = (float*)(ws + (56u<<20));                      // 16 KB
  float* scale = upart + BB*8*256;                              // 32 floats

  u1_partial<<<dim3(8, BB), 256, 0, stream>>>(ue, Wu1, upart);
  u2_scale<<<BB, 256, 0, stream>>>(upart, bu1, Wu2, bu2, scale);
  maskprep_kernel<<<(BB*NHEADS*LL/8)/256, 256, 0, stream>>>(amask, scale, maskf);
  convert_x_kernel<<<(MM*HID/4)/256, 256, 0, stream>>>(hidden, Xbf);
  transw_kernel<<<dim3(32, 32, 4), dim3(32, 8), 0, stream>>>(Wq, Wk, Wv, Wo, Wqkvt, Wot);
  gemm_kernel<0><<<1536, 256, 0, stream>>>(Xbf, Wqkvt,
                                           bq, bk, bv, nullptr, Qb, nullptr);
  attn_kernel<<<BB*NHEADS*(LL/64), 256, 0, stream>>>(Qb, Kb, Vb, maskf, scale, AOut);
  gemm_kernel<1><<<512, 256, 0, stream>>>(AOut, Wot,
                                          bo, nullptr, nullptr, hidden, nullptr, Y);
  ln_kernel<<<MM, 256, 0, stream>>>(Y, gamma, beta, out);
}

// Round 17
// 144.664 us; speedup vs baseline: 1.0649x; 1.0578x over previous
//
#include <hip/hip_runtime.h>
#include <hip/hip_bf16.h>

#define HID 1024
#define NHEADS 16
#define DH 64
#define BB 2
#define LL 2048
#define MM (BB*LL)   // 4096 rows
#define EPSF 1e-5f

typedef __attribute__((ext_vector_type(8))) short bf16x8;
typedef __attribute__((ext_vector_type(4))) float f32x4;

#define MFMA16(A,Bf,C) __builtin_amdgcn_mfma_f32_16x16x32_bf16(A,Bf,C,0,0,0)
#define GLOAD_LDS16(G, Ld) \
  __builtin_amdgcn_global_load_lds((__attribute__((address_space(1))) const void*)(G), \
                                   (__attribute__((address_space(3))) void*)(Ld), 16, 0, 0)
#define PIN(v) asm("" : "+v"(v))   // pin loop-invariant addr in a VGPR (no remat)
// raw v_exp_f32: args here are in [-30,-13] (normal results) — OCML's
// range/denorm guard code (~12 VALU ops per call) is pure overhead.
#define EXP2R(x) ({ float _y; asm("v_exp_f32 %0, %1" : "=v"(_y) : "v"(x)); _y; })
// Publish/consume barrier for the 2-phase LDS double-buffer.
// MUST drain BOTH counters: vmcnt(0) completes our global_load_lds DMA
// (publish side); lgkmcnt(0) completes our ds_reads of the buffer that the
// next phase will overwrite (consume side). s_barrier alone does NOT wait
// on other waves' outstanding LDS ops — omitting lgkmcnt(0) is a cross-wave
// race (R14 post-timing divergence: DMA landed in a buffer still being read).
#define WAIT_VM0_BAR() do { \
    asm volatile("s_waitcnt vmcnt(0) lgkmcnt(0)" ::: "memory"); \
    __builtin_amdgcn_s_barrier(); \
    __builtin_amdgcn_sched_barrier(0); \
  } while (0)

__device__ __forceinline__ unsigned short f2bf(float f) {
  union { float f; unsigned int u; } x; x.f = f;
  unsigned int r = x.u + 0x7fffu + ((x.u >> 16) & 1u);
  return (unsigned short)(r >> 16);
}

// ---------------- uncertainty gate: u = relu(ue@Wu1+bu1); scale = sigmoid(u@Wu2+bu2)
__global__ __launch_bounds__(256) void u1_partial(const float* __restrict__ ue,
                                                  const float* __restrict__ Wu1,
                                                  float* __restrict__ upart) {
  int b = blockIdx.y, kb = blockIdx.x;           // kb: 0..7, 128 k each
  __shared__ float su[128];
  int tid = threadIdx.x;
  if (tid < 128) su[tid] = ue[b*HID + kb*128 + tid];
  __syncthreads();
  float s = 0.f;
  const float* w = Wu1 + (size_t)(kb*128)*256 + tid;  // column tid
  for (int k = 0; k < 128; ++k) s += su[k] * w[(size_t)k*256];
  upart[(b*8 + kb)*256 + tid] = s;
}

__global__ __launch_bounds__(256) void u2_scale(const float* __restrict__ upart,
                                                const float* __restrict__ bu1,
                                                const float* __restrict__ Wu2,
                                                const float* __restrict__ bu2,
                                                float* __restrict__ scale) {
  int b = blockIdx.x, tid = threadIdx.x;
  __shared__ float su[256];
  float s = 0.f;
  for (int kb = 0; kb < 8; ++kb) s += upart[(b*8 + kb)*256 + tid];
  su[tid] = fmaxf(s + bu1[tid], 0.f);
  __syncthreads();
  if (tid < 16) {
    float a = bu2[tid];
    for (int k = 0; k < 256; ++k) a += su[k] * Wu2[k*16 + tid];
    scale[b*NHEADS + tid] = 1.f / (1.f + __expf(-a));
  }
}

// ---------------- maskf[bh][k] = (amask==0 ? -1e9 : 0)*scale[bh]*log2e - CFIX
// CFIX=16: fixed softmax shift (shift-invariant; scores are O(1) in log2
// units, exp2(s-16) in [2^-20,2^-13] — no overflow/all-underflow here).
__global__ __launch_bounds__(256) void maskprep_kernel(const int* __restrict__ amask,
                                                       const float* __restrict__ scale,
                                                       float* __restrict__ maskf) {
  int i = blockIdx.x*256 + threadIdx.x;   // 8 elems each; total 32*2048
  int base = i*8;
  int bh = base >> 11;
  int b  = bh >> 4;
  float cm = scale[bh] * 1.44269504f;
  int k = base & (LL-1);
  #pragma unroll
  for (int j = 0; j < 8; ++j)
    maskf[base + j] = (amask[b*LL + k + j] == 0 ? -1e9f : 0.f) * cm - 16.f;
}

// ---------------- fp32 -> bf16 convert (hidden_state)
__global__ __launch_bounds__(256) void convert_x_kernel(const float* __restrict__ X,
                                                        unsigned short* __restrict__ Xb) {
  int i = blockIdx.x*256 + threadIdx.x;   // 4 elems each; grid sized exactly
  float4 v = ((const float4*)X)[i];
  ushort4 o; o.x = f2bf(v.x); o.y = f2bf(v.y); o.z = f2bf(v.z); o.w = f2bf(v.w);
  ((ushort4*)Xb)[i] = o;
}

// ---------------- W (K x N fp32) -> Wt (N x K bf16), z selects Wq/Wk/Wv/Wo
__global__ void transw_kernel(const float* __restrict__ Wq, const float* __restrict__ Wk,
                              const float* __restrict__ Wv, const float* __restrict__ Wo,
                              unsigned short* __restrict__ Wqkvt, unsigned short* __restrict__ Wot) {
  __shared__ float tile[32][33];
  int z = blockIdx.z;
  const float* W = (z==0) ? Wq : (z==1) ? Wk : (z==2) ? Wv : Wo;
  unsigned short* dst = (z < 3) ? (Wqkvt + (size_t)z*HID*HID) : Wot;
  int n0 = blockIdx.x*32, k0 = blockIdx.y*32;
  int tx = threadIdx.x, ty = threadIdx.y;      // 32 x 8
  #pragma unroll
  for (int i = 0; i < 4; ++i) tile[ty+8*i][tx] = W[(size_t)(k0+ty+8*i)*HID + n0+tx];
  __syncthreads();
  #pragma unroll
  for (int i = 0; i < 4; ++i) dst[(size_t)(n0+ty+8*i)*HID + k0+tx] = f2bf(tile[tx][ty+8*i]);
}

// ---------------- MFMA GEMM, BK=64, K=HID: C = A @ Bt^T (+epilogues)
// R9-proven structure (best total: 144.8us) + R15 race fix in the barrier.
// 2-phase dbuf, one vmcnt(0)+lgkmcnt(0)+s_barrier per 64-K-step.
// MODE 0: 128x128 tile, grid 768 (1D); QKV -> bf16; Q,K (b,h,l,d); V (b,h,d,l)
// MODE 1: 64x128 tile,  grid 512 (1D); out-proj -> fp32 y = C + bo + hidden
// XCD-aware decode: XCD x owns an n-slice. LDS rows 128B, XOR-swizzled
// physical = row*128 + (colByte ^ ((row&7)<<4)).
template<int MODE>
__global__ __launch_bounds__(256) void gemm_kernel(
    const unsigned short* __restrict__ A,
    const unsigned short* __restrict__ Bt,
    const float* __restrict__ bias0, const float* __restrict__ bias1, const float* __restrict__ bias2,
    const float* __restrict__ resid,
    unsigned short* __restrict__ outQKV,
    float* __restrict__ outY) {
  constexpr int BM = (MODE == 0) ? 128 : 64;
  constexpr int MI = BM / 32;                 // acc rows per wave (4 or 2)
  constexpr int ASZ = BM*64*2;                // bytes per A buffer
  constexpr int BSZ = 128*64*2;               // bytes per B buffer
  __shared__ alignas(16) unsigned short sA[2*BM*64];
  __shared__ alignas(16) unsigned short sB[2*128*64];
  const int tid = threadIdx.x, lane = tid & 63, wv = tid >> 6;
  const int wr = wv >> 1, wc = wv & 1;
  const int bid = blockIdx.x, xcd = bid & 7, loc = bid >> 3;
  const int nIdx = (MODE == 0) ? (xcd*3 + loc % 3) : xcd;
  const int mIdx = (MODE == 0) ? (loc / 3) : loc;
  const int m0 = mIdx*BM, n0 = nIdx*128;
  const int r = lane & 15, g = lane >> 4;

  const unsigned short* pA[MI];
  const unsigned short* pB[4];
  int ldsA[MI], ldsB[4];
  #pragma unroll
  for (int c = 0; c < MI; ++c) {
    const int base = c*4096 + wv*1024;
    const int po = base + lane*16;
    const int uo = po ^ (((po>>7)&7)<<4);
    const int e  = uo >> 1;                   // row=e>>6, col=e&63
    pA[c] = A + (size_t)(m0 + (e>>6))*HID + (e&63);
    ldsA[c] = base;
  }
  #pragma unroll
  for (int c = 0; c < 4; ++c) {
    const int base = c*4096 + wv*1024;
    const int po = base + lane*16;
    const int uo = po ^ (((po>>7)&7)<<4);
    const int e  = uo >> 1;
    pB[c] = Bt + (size_t)(n0 + (e>>6))*HID + (e&63);
    ldsB[c] = base;
  }
  const int sw = (r & 7) << 4;
  int oALo = (wr*(MI*16) + r)*128 + ((g*16) ^ sw);
  int oAHi = (wr*(MI*16) + r)*128 + ((64 + g*16) ^ sw);
  int oBLo = (wc*64 + r)*128 + ((g*16) ^ sw);
  int oBHi = (wc*64 + r)*128 + ((64 + g*16) ^ sw);
  PIN(oALo); PIN(oAHi); PIN(oBLo); PIN(oBHi);

#define GSTAGE(BUF) do {                                                      \
    _Pragma("unroll")                                                         \
    for (int c = 0; c < MI; ++c) {                                            \
      GLOAD_LDS16(pA[c], (char*)sA + (BUF)*ASZ + ldsA[c]); pA[c] += 64;       \
    }                                                                         \
    _Pragma("unroll")                                                         \
    for (int c = 0; c < 4; ++c) {                                             \
      GLOAD_LDS16(pB[c], (char*)sB + (BUF)*BSZ + ldsB[c]); pB[c] += 64;       \
    }                                                                         \
  } while (0)

#define GCOMPUTE(BUF) do {                                                    \
    _Pragma("unroll")                                                         \
    for (int kk = 0; kk < 2; ++kk) {                                          \
      bf16x8 af[MI], bfv[4];                                                  \
      _Pragma("unroll")                                                       \
      for (int i = 0; i < MI; ++i)                                            \
        af[i]  = *(const bf16x8*)((const char*)sA + (BUF)*ASZ +               \
                                  (kk ? oAHi : oALo) + i*2048);               \
      _Pragma("unroll")                                                       \
      for (int j = 0; j < 4; ++j)                                             \
        bfv[j] = *(const bf16x8*)((const char*)sB + (BUF)*BSZ +               \
                                  (kk ? oBHi : oBLo) + j*2048);               \
      __builtin_amdgcn_s_setprio(1);                                          \
      _Pragma("unroll")                                                       \
      for (int i = 0; i < MI; ++i)                                            \
        _Pragma("unroll")                                                     \
        for (int j = 0; j < 4; ++j)                                           \
          acc[i][j] = MFMA16(af[i], bfv[j], acc[i][j]);                       \
      __builtin_amdgcn_s_setprio(0);                                          \
    }                                                                         \
  } while (0)

  f32x4 acc[MI][4];
  #pragma unroll
  for (int i = 0; i < MI; ++i)
    #pragma unroll
    for (int j = 0; j < 4; ++j) acc[i][j] = (f32x4){0.f,0.f,0.f,0.f};

  GSTAGE(0);                                  // prologue: K-step 0 -> buf0
  for (int k0 = 0; k0 < HID; k0 += 128) {     // 8 double-steps
    WAIT_VM0_BAR();                           // buf0 ready (staged 1 phase ago)
    GSTAGE(1);                                // next step -> buf1 (always valid)
    GCOMPUTE(0);
    WAIT_VM0_BAR();                           // buf1 ready
    if (k0 + 128 < HID) GSTAGE(0);
    GCOMPUTE(1);
  }
#undef GSTAGE
#undef GCOMPUTE

  if (MODE == 0) {
    const int which = n0 >> 10;
    const float* bias = (which==0) ? bias0 : (which==1) ? bias1 : bias2;
    if (which < 2) {
      unsigned short* dst = outQKV + (size_t)which * ((size_t)MM*HID);
      #pragma unroll
      for (int i = 0; i < MI; ++i)
        #pragma unroll
        for (int j = 0; j < 4; ++j)
          #pragma unroll
          for (int rr = 0; rr < 4; ++rr) {
            int row = m0 + wr*(MI*16) + i*16 + g*4 + rr;
            int col = n0 + wc*64 + j*16 + r;
            int nn = col & (HID-1);
            int hh = nn >> 6, d = nn & 63;
            int bI = row >> 11, l = row & (LL-1);
            float v = acc[i][j][rr] + bias[nn];
            dst[(((size_t)(bI*NHEADS + hh)*LL + l) << 6) + d] = f2bf(v);
          }
    } else {
      unsigned short* dst = outQKV + 2*((size_t)MM*HID);
      #pragma unroll
      for (int i = 0; i < MI; ++i)
        #pragma unroll
        for (int j = 0; j < 4; ++j) {
          int col = n0 + wc*64 + j*16 + r;
          int nn = col & (HID-1);
          int hh = nn >> 6, d = nn & 63;
          int row0 = m0 + wr*(MI*16) + i*16 + g*4;
          int bI = row0 >> 11, l0 = row0 & (LL-1);
          ushort4 o4;
          o4.x = f2bf(acc[i][j][0] + bias[nn]);
          o4.y = f2bf(acc[i][j][1] + bias[nn]);
          o4.z = f2bf(acc[i][j][2] + bias[nn]);
          o4.w = f2bf(acc[i][j][3] + bias[nn]);
          *(ushort4*)(dst + ((size_t)((bI*NHEADS + hh)*DH + d))*LL + l0) = o4;
        }
    }
  } else {
    #pragma unroll
    for (int i = 0; i < MI; ++i)
      #pragma unroll
      for (int j = 0; j < 4; ++j)
        #pragma unroll
        for (int rr = 0; rr < 4; ++rr) {
          int row = m0 + wr*(MI*16) + i*16 + g*4 + rr;
          int col = n0 + wc*64 + j*16 + r;
          size_t idx = (size_t)row*HID + col;
          outY[idx] = acc[i][j][rr] + bias0[col] + resid[idx];
        }
  }
}

// ---------------- flash attention (R9 structure): block = (b,h, 64 q);
// 4 waves x 16 q. 2-phase gload_lds dbuf K+V (pre-swizzled source, linear
// dest), ONE vmcnt(0)+lgkmcnt(0)+s_barrier per tile; fixed-exponent softmax;
// l via persistent ones-MFMA; raw v_exp_f32. LDS 40KB = 4 blocks/CU.
__global__ __launch_bounds__(256, 4) void attn_kernel(
    const unsigned short* __restrict__ Qb,
    const unsigned short* __restrict__ Kb,
    const unsigned short* __restrict__ Vt,
    const float* __restrict__ maskf,
    const float* __restrict__ scale_ws,
    unsigned short* __restrict__ attnout) {
  __shared__ alignas(16) unsigned short sK[2*64*64];  // [buf][key][d] (swizzled)
  __shared__ alignas(16) unsigned short sV[2*64*64];  // [buf][d][key] (swizzled)
  __shared__ alignas(16) unsigned short sP[4][16*64]; // per-wave [q][key] (swizzled)
  const int p = blockIdx.x;
  const int bh = (p & 7)*4 + ((p >> 3) >> 5);
  const int q0 = ((p >> 3) & 31) * 64;
  const int b  = bh >> 4;
  const int tid = threadIdx.x, lane = tid & 63, wv = tid >> 6;
  const int r = lane & 15, g = lane >> 4;
  const size_t hoff = (size_t)bh * (LL*DH);
  const float c2 = 0.125f * scale_ws[bh] * 1.44269504f;
  const unsigned short* Kg = Kb + hoff;
  const unsigned short* Vg = Vt + hoff;
  const float* pm = maskf + (size_t)bh*LL + g*4;

  // staging: 2 gload_lds each for K and V; source pre-swizzled, dest linear
  const unsigned short* pKs[2];
  const unsigned short* pVs[2];
  int lbase[2];
  #pragma unroll
  for (int c = 0; c < 2; ++c) {
    const int base_ = c*4096 + wv*1024;
    const int po_ = base_ + lane*16;
    const int uo_ = po_ ^ (((po_>>7)&7)<<4);
    const int e_  = uo_ >> 1;                 // row=e>>6, col=e&63
    pKs[c] = Kg + (size_t)(e_>>6)*DH + (e_&63);
    pVs[c] = Vg + (size_t)(e_>>6)*LL + (e_&63);
    lbase[c] = base_;
  }

  // pinned LDS read bases (shared by sK, sV, sP via array base + offset)
  const int sw = (r & 7) << 4;
  int oLo = r*128 + ((g*16) ^ sw);
  int oHi = r*128 + ((64 + g*16) ^ sw);
  PIN(oLo); PIN(oHi);
  int wP[4];
  #pragma unroll
  for (int kt = 0; kt < 4; ++kt) {
    wP[kt] = r*128 + ((kt*32 + g*8) ^ sw);
    PIN(wP[kt]);
  }

  bf16x8 aQ[2];                // Q B-frags: col=q=lane&15, k contiguous
  {
    const int qrow = q0 + wv*16 + r;
    #pragma unroll
    for (int kc = 0; kc < 2; ++kc)
      aQ[kc] = *(const bf16x8*)(Qb + hoff + (size_t)qrow*DH + kc*32 + g*8);
  }
  const short ONE_BF = (short)0x3F80;
  const bf16x8 vone = {ONE_BF,ONE_BF,ONE_BF,ONE_BF,ONE_BF,ONE_BF,ONE_BF,ONE_BF};

  f32x4 accO[4];               // accO[j][rr]: q=r, d=j*16+g*4+rr
  #pragma unroll
  for (int j = 0; j < 4; ++j) accO[j] = (f32x4){0.f,0.f,0.f,0.f};
  f32x4 lsum = (f32x4){0.f,0.f,0.f,0.f};   // persistent denominator accumulator

  // prologue: stage tile 0 -> buf0; mask(0) -> regs
  #pragma unroll
  for (int c = 0; c < 2; ++c) {
    GLOAD_LDS16(pKs[c], (char*)sK + lbase[c]);
    GLOAD_LDS16(pVs[c], (char*)sV + lbase[c]);
    pKs[c] += 64*DH;  pVs[c] += 64;
  }
  float4 mreg[4];
  #pragma unroll
  for (int kt = 0; kt < 4; ++kt) mreg[kt] = *(const float4*)(pm + kt*16);
  pm += 64;

#define ATILE(CUROFF, NBOFF, T) do {                                          \
    WAIT_VM0_BAR();                       /* tile T staged & published */     \
    if ((T) + 1 < LL/64) {                /* stage T+1 -> other buffer */     \
      _Pragma("unroll")                                                       \
      for (int c = 0; c < 2; ++c) {                                           \
        GLOAD_LDS16(pKs[c], (char*)sK + (NBOFF) + lbase[c]);                  \
        GLOAD_LDS16(pVs[c], (char*)sV + (NBOFF) + lbase[c]);                  \
        pKs[c] += 64*DH;  pVs[c] += 64;                                       \
      }                                                                       \
    }                                                                         \
    f32x4 sc[4];                                                              \
    __builtin_amdgcn_s_setprio(1);                                            \
    _Pragma("unroll")                                                         \
    for (int kt = 0; kt < 4; ++kt) {                                          \
      bf16x8 bk0 = *(const bf16x8*)((const char*)sK + (CUROFF) + oLo + kt*2048); \
      bf16x8 bk1 = *(const bf16x8*)((const char*)sK + (CUROFF) + oHi + kt*2048); \
      f32x4 a = (f32x4){0.f,0.f,0.f,0.f};                                     \
      a = MFMA16(bk0, aQ[0], a);                                              \
      a = MFMA16(bk1, aQ[1], a);                                              \
      sc[kt] = a;                                                             \
    }                                                                         \
    __builtin_amdgcn_s_setprio(0);                                            \
    _Pragma("unroll")                                                         \
    for (int kt = 0; kt < 4; ++kt) {                                          \
      sc[kt][0] = EXP2R(sc[kt][0]*c2 + mreg[kt].x);                           \
      sc[kt][1] = EXP2R(sc[kt][1]*c2 + mreg[kt].y);                           \
      sc[kt][2] = EXP2R(sc[kt][2]*c2 + mreg[kt].z);                           \
      sc[kt][3] = EXP2R(sc[kt][3]*c2 + mreg[kt].w);                           \
    }                                                                         \
    if ((T) + 1 < LL/64) {                                                    \
      _Pragma("unroll")                                                       \
      for (int kt = 0; kt < 4; ++kt) mreg[kt] = *(const float4*)(pm + kt*16); \
      pm += 64;                                                               \
    }                                                                         \
    char* sPw = (char*)sP[wv];                                                \
    _Pragma("unroll")                                                         \
    for (int kt = 0; kt < 4; ++kt) {                                          \
      unsigned int lo, hi;                                                    \
      asm("v_cvt_pk_bf16_f32 %0, %1, %2" : "=v"(lo) : "v"(sc[kt][0]), "v"(sc[kt][1])); \
      asm("v_cvt_pk_bf16_f32 %0, %1, %2" : "=v"(hi) : "v"(sc[kt][2]), "v"(sc[kt][3])); \
      uint2 w; w.x = lo; w.y = hi;                                            \
      *(uint2*)(sPw + wP[kt]) = w;                                            \
    }                                                                         \
    bf16x8 aP0 = *(const bf16x8*)(sPw + oLo);                                 \
    bf16x8 aP1 = *(const bf16x8*)(sPw + oHi);                                 \
    lsum = MFMA16(vone, aP0, lsum);                                           \
    lsum = MFMA16(vone, aP1, lsum);                                           \
    __builtin_amdgcn_s_setprio(1);                                            \
    _Pragma("unroll")                                                         \
    for (int j = 0; j < 4; ++j) {                                             \
      bf16x8 v0 = *(const bf16x8*)((const char*)sV + (CUROFF) + oLo + j*2048); \
      bf16x8 v1 = *(const bf16x8*)((const char*)sV + (CUROFF) + oHi + j*2048); \
      accO[j] = MFMA16(v0, aP0, accO[j]);                                     \
      accO[j] = MFMA16(v1, aP1, accO[j]);                                     \
    }                                                                         \
    __builtin_amdgcn_s_setprio(0);                                            \
  } while (0)

  for (int t = 0; t < LL/64; t += 2) {
    ATILE(0,    8192, t);
    ATILE(8192, 0,    t+1);
  }
#undef ATILE

  // write (b, l, h*64+d) bf16; lane-local l, vectorized ushort4 stores
  const float invl = 1.f / lsum[0];
  const int qq = q0 + wv*16 + r;
  #pragma unroll
  for (int j = 0; j < 4; ++j) {
    ushort4 o4;
    o4.x = f2bf(accO[j][0] * invl);
    o4.y = f2bf(accO[j][1] * invl);
    o4.z = f2bf(accO[j][2] * invl);
    o4.w = f2bf(accO[j][3] * invl);
    const int col = (bh & 15)*DH + j*16 + g*4;
    *(ushort4*)(attnout + (size_t)(b*LL + qq)*HID + col) = o4;
  }
}

// ---------------- LayerNorm over last dim (1024), fp32 in/out (float4 loads)
__global__ __launch_bounds__(256) void ln_kernel(const float* __restrict__ Y,
                                                 const float* __restrict__ gamma,
                                                 const float* __restrict__ beta,
                                                 float* __restrict__ out) {
  int row = blockIdx.x, tid = threadIdx.x;
  const float4 v = ((const float4*)(Y + (size_t)row*HID))[tid];
  float s  = (v.x + v.y) + (v.z + v.w);
  float s2 = (v.x*v.x + v.y*v.y) + (v.z*v.z + v.w*v.w);
  #pragma unroll
  for (int o = 1; o < 64; o <<= 1) { s += __shfl_xor(s, o, 64); s2 += __shfl_xor(s2, o, 64); }
  __shared__ float ws1[4], ws2[4];
  if ((tid & 63) == 0) { ws1[tid>>6] = s; ws2[tid>>6] = s2; }
  __syncthreads();
  s  = ws1[0] + ws1[1] + ws1[2] + ws1[3];
  s2 = ws2[0] + ws2[1] + ws2[2] + ws2[3];
  float mu  = s * (1.f/HID);
  float var = s2 * (1.f/HID) - mu*mu;
  float rs  = rsqrtf(var + EPSF);
  const float4 gm = ((const float4*)gamma)[tid];
  const float4 bt = ((const float4*)beta)[tid];
  float4 o4;
  o4.x = (v.x - mu)*rs*gm.x + bt.x;
  o4.y = (v.y - mu)*rs*gm.y + bt.y;
  o4.z = (v.z - mu)*rs*gm.z + bt.z;
  o4.w = (v.w - mu)*rs*gm.w + bt.w;
  ((float4*)(out + (size_t)row*HID))[tid] = o4;
}

extern "C" void kernel_launch(void* const* d_in, const int* in_sizes, int n_in,
                              void* d_out, int out_size, void* d_ws, size_t ws_size,
                              hipStream_t stream) {
  const float* hidden = (const float*)d_in[0];
  const float* ue     = (const float*)d_in[1];
  const int*   amask  = (const int*)d_in[2];
  const float* Wq = (const float*)d_in[3];  const float* bq = (const float*)d_in[4];
  const float* Wk = (const float*)d_in[5];  const float* bk = (const float*)d_in[6];
  const float* Wv = (const float*)d_in[7];  const float* bv = (const float*)d_in[8];
  const float* Wo = (const float*)d_in[9];  const float* bo = (const float*)d_in[10];
  const float* Wu1 = (const float*)d_in[11]; const float* bu1 = (const float*)d_in[12];
  const float* Wu2 = (const float*)d_in[13]; const float* bu2 = (const float*)d_in[14];
  const float* gamma = (const float*)d_in[15]; const float* beta = (const float*)d_in[16];
  float* out = (float*)d_out;

  // workspace layout (needs ~57 MB)
  char* ws = (char*)d_ws;
  if (ws_size < ((56u<<20) + 32768)) return;
  unsigned short* Xbf   = (unsigned short*)(ws + 0);            // 8 MB (dead after QKV gemm)
  float*          Y     = (float*)(ws + 0);                     // 16 MB (written by gemm1, after attn)
  float*          maskf = (float*)(ws + (8u<<20));              // 256 KB (dead once gemm1 writes Y)
  unsigned short* Wqkvt = (unsigned short*)(ws + (16u<<20));    // 6 MB
  unsigned short* Wot   = (unsigned short*)(ws + (22u<<20));    // 2 MB
  unsigned short* Qb    = (unsigned short*)(ws + (24u<<20));    // 8 MB each
  unsigned short* Kb    = Qb + (size_t)MM*HID;
  unsigned short* Vb    = Kb + (size_t)MM*HID;                  // V^T (b,h,d,l)
  unsigned short* AOut  = (unsigned short*)(ws + (48u<<20));    // 8 MB
  float* upart = (float*)(ws + (56u<<20));                      // 16 KB
  float* scale = upart + BB*8*256;                              // 32 floats

  u1_partial<<<dim3(8, BB), 256, 0, stream>>>(ue, Wu1, upart);
  u2_scale<<<BB, 256, 0, stream>>>(upart, bu1, Wu2, bu2, scale);
  maskprep_kernel<<<(BB*NHEADS*LL/8)/256, 256, 0, stream>>>(amask, scale, maskf);
  convert_x_kernel<<<(MM*HID/4)/256, 256, 0, stream>>>(hidden, Xbf);
  transw_kernel<<<dim3(32, 32, 4), dim3(32, 8), 0, stream>>>(Wq, Wk, Wv, Wo, Wqkvt, Wot);
  gemm_kernel<0><<<768, 256, 0, stream>>>(Xbf, Wqkvt,
                                          bq, bk, bv, nullptr, Qb, nullptr);
  attn_kernel<<<BB*NHEADS*(LL/64), 256, 0, stream>>>(Qb, Kb, Vb, maskf, scale, AOut);
  gemm_kernel<1><<<512, 256, 0, stream>>>(AOut, Wot,
                                          bo, nullptr, nullptr, hidden, nullptr, Y);
  ln_kernel<<<MM, 256, 0, stream>>>(Y, gamma, beta, out);
}